// Round 11
// baseline (159.492 us; speedup 1.0000x reference)
//
#include <hip/hip_runtime.h>

#define NB 2
#define NC 16
#define NH 128
#define NW 256
#define NCW 32
#define HW (NH*NW)
#define PATCH_INV (1.0f/784.0f)
#define EPS_N 1e-9f
#define HB_W 272   // hbuf row: [0..3]=0, [4..259]=prod cols 0..255, [260..271]=0

// One block per (b,y); 256 threads = 64 x-groups (4 cols) x 4 d-groups (8 disps).
// cost[b,y,x,d] = (S_LR - SL*SR/784) * invL * invR, separable 7x7 box sums.
// launch_bounds(256,1): unlock VGPRs so the unrolled phase-C loop can prefetch.
__global__ __launch_bounds__(256, 1) void ncc_kernel(
    const float* __restrict__ L, const float* __restrict__ R, float* __restrict__ out)
{
    __shared__ float psum[2][2][64][8];   // [img][dyhalf][colquad][s0..3,s2_0..3]
    __shared__ float csL[NW], cs2L[NW], csR[NW], cs2R[NW];
    __shared__ float sSL[288], sInvL[288], sSR[NW], sInvR[NW];
    __shared__ float hbuf[NCW][HB_W];

    // XCD-aware bijective swizzle (256 = 8 XCDs x 32 consecutive rows)
    const int bid = blockIdx.x;
    const int lin = (bid & 7) * 32 + (bid >> 3);
    const int b = lin >> 7;
    const int y = lin & 127;

    const int t  = threadIdx.x;
    const int dq = t >> 6;           // 0..3
    const int xg = t & 63;
    const int x0 = xg << 2;
    const int d0 = dq << 3;
    const int s  = x0 + d0;          // left window base (<=276), multiple of 4

    const size_t base = (size_t)b * NC * HW;

    // ---- phase A: column stats, vectorized; job = (img, dy-half, col-quad) ----
    {
        const int img = t >> 7;               // wave-uniform
        const int dyh = (t >> 6) & 1;         // wave-uniform
        const int q   = t & 63;
        const float* I = img ? R : L;
        const int dy0 = dyh ? 4 : 0;
        const int ndy = dyh ? 3 : 4;
        float s0=0.f,s1=0.f,s2v=0.f,s3=0.f, q0=0.f,q1=0.f,q2=0.f,q3=0.f;
        #pragma unroll
        for (int k = 0; k < 4; ++k) {
            if (k < ndy) {                    // wave-uniform guard
                const int yy  = y - 3 + dy0 + k;
                const int yyc = yy < 0 ? 0 : (yy > NH - 1 ? NH - 1 : yy);
                const float m = ((unsigned)yy < NH) ? 1.f : 0.f;
                const float* p = I + base + (size_t)yyc * NW + (q << 2);
                #pragma unroll
                for (int c = 0; c < NC; ++c) {
                    float4 v = *(const float4*)(p + (size_t)c * HW);
                    float a0 = m * v.x, a1 = m * v.y, a2 = m * v.z, a3 = m * v.w;
                    s0 += a0; s1 += a1; s2v += a2; s3 += a3;
                    q0 += a0 * v.x; q1 += a1 * v.y; q2 += a2 * v.z; q3 += a3 * v.w;
                }
            }
        }
        psum[img][dyh][q][0] = s0; psum[img][dyh][q][1] = s1;
        psum[img][dyh][q][2] = s2v; psum[img][dyh][q][3] = s3;
        psum[img][dyh][q][4] = q0; psum[img][dyh][q][5] = q1;
        psum[img][dyh][q][6] = q2; psum[img][dyh][q][7] = q3;
    }
    __syncthreads();

    // ---- phase A2: combine dy-halves -> cs arrays (thread t = column t) ----
    {
        const int q = t >> 2, r = t & 3;
        csL[t]  = psum[0][0][q][r]     + psum[0][1][q][r];
        cs2L[t] = psum[0][0][q][r + 4] + psum[0][1][q][r + 4];
        csR[t]  = psum[1][0][q][r]     + psum[1][1][q][r];
        cs2R[t] = psum[1][0][q][r + 4] + psum[1][1][q][r + 4];
    }
    __syncthreads();

    // ---- phase B: horizontal 7-tap -> per-pixel patch stats (r4 verbatim) ----
    #pragma unroll
    for (int rep = 0; rep < 2; ++rep) {
        int xe = t + rep * 256;
        if (xe < 288) {
            float S = 0.f, S2 = 0.f;
            #pragma unroll
            for (int dx = -3; dx <= 3; ++dx) {
                int xx = xe + dx;
                if ((unsigned)xx < NW) { S += csL[xx]; S2 += cs2L[xx]; }
            }
            sSL[xe]   = S;
            sInvL[xe] = rsqrtf(S2 - S * S * PATCH_INV + EPS_N);
        }
    }
    {
        float S = 0.f, S2 = 0.f;
        #pragma unroll
        for (int dx = -3; dx <= 3; ++dx) {
            int xx = t + dx;
            if ((unsigned)xx < NW) { S += csR[xx]; S2 += cs2R[xx]; }
        }
        sSR[t]   = S;
        sInvR[t] = rsqrtf(S2 - S * S * PATCH_INV + EPS_N);
    }
    __syncthreads();

    // ---- phase C: product sums, 4 cols x 8 disps; unconditional clamp+mask rows ----
    float vp[4][8];
    #pragma unroll
    for (int i = 0; i < 4; ++i)
        #pragma unroll
        for (int j = 0; j < 8; ++j) vp[i][j] = 0.f;

    #pragma unroll
    for (int k = 0; k < 7; ++k) {
        const int yy  = y - 3 + k;
        const int yyc = yy < 0 ? 0 : (yy > NH - 1 ? NH - 1 : yy);
        const float rm = ((unsigned)yy < NH) ? 1.f : 0.f;
        const float* lrow = L + base + (size_t)yyc * NW;
        const float* rrow = R + base + (size_t)yyc * NW;
        #pragma unroll
        for (int c = 0; c < NC; ++c) {
            const float* lc = lrow + (size_t)c * HW;
            const float* rc = rrow + (size_t)c * HW;
            float4 rv4 = *(const float4*)(rc + x0);
            float rv[4] = {rm * rv4.x, rm * rv4.y, rm * rv4.z, rm * rv4.w};
            float lw[12];
            #pragma unroll
            for (int ch = 0; ch < 3; ++ch) {
                int col  = s + ch * 4;                       // multiple of 4
                int colc = col < (NW - 4) ? col : (NW - 4);  // always-valid addr
                float4 lv = *(const float4*)(lc + colc);
                bool ok = (col < NW);                        // ext region zero
                lw[ch*4+0] = ok ? lv.x : 0.f;
                lw[ch*4+1] = ok ? lv.y : 0.f;
                lw[ch*4+2] = ok ? lv.z : 0.f;
                lw[ch*4+3] = ok ? lv.w : 0.f;
            }
            #pragma unroll
            for (int xx = 0; xx < 4; ++xx)
                #pragma unroll
                for (int j = 0; j < 8; ++j)
                    vp[xx][j] += lw[xx + j] * rv[xx];
        }
    }
    #pragma unroll
    for (int j = 0; j < 8; ++j)
        *(float4*)&hbuf[d0 + j][4 + x0] =
            make_float4(vp[0][j], vp[1][j], vp[2][j], vp[3][j]);
    if (t < 128) {   // zero halo pads: cols 0..3 and 260..271 of each d-row
        int r = t >> 2, q = t & 3;
        int col = (q == 0) ? 0 : (260 + 4 * (q - 1));
        *(float4*)&hbuf[r][col] = make_float4(0.f, 0.f, 0.f, 0.f);
    }
    __syncthreads();

    // ---- phase D: ascending 7-tap + normalize + store (r4 verbatim) ----
    float res[4][8];
    #pragma unroll
    for (int j = 0; j < 8; ++j) {
        float4 w0 = *(float4*)&hbuf[d0+j][x0];
        float4 w1 = *(float4*)&hbuf[d0+j][x0+4];
        float4 w2 = *(float4*)&hbuf[d0+j][x0+8];
        float w[12] = {w0.x,w0.y,w0.z,w0.w, w1.x,w1.y,w1.z,w1.w, w2.x,w2.y,w2.z,w2.w};
        #pragma unroll
        for (int xx = 0; xx < 4; ++xx) {
            float sum = 0.f;
            #pragma unroll
            for (int k = 1; k <= 7; ++k) sum += w[xx + k];
            float slv = sSL[s + xx + j];
            float ilv = sInvL[s + xx + j];
            float srv = sSR[x0 + xx];
            float irv = sInvR[x0 + xx];
            res[xx][j] = (sum - slv * srv * PATCH_INV) * ilv * irv;
        }
    }

    float* op = out + (((size_t)(b * NH + y) * NW) + x0) * NCW + d0;
    #pragma unroll
    for (int xx = 0; xx < 4; ++xx) {
        *(float4*)(op + (size_t)xx * NCW)     =
            make_float4(res[xx][0], res[xx][1], res[xx][2], res[xx][3]);
        *(float4*)(op + (size_t)xx * NCW + 4) =
            make_float4(res[xx][4], res[xx][5], res[xx][6], res[xx][7]);
    }
}

extern "C" void kernel_launch(void* const* d_in, const int* in_sizes, int n_in,
                              void* d_out, int out_size, void* d_ws, size_t ws_size,
                              hipStream_t stream) {
    const float* L = (const float*)d_in[0];
    const float* R = (const float*)d_in[1];
    float* out = (float*)d_out;
    ncc_kernel<<<dim3(NB * NH), dim3(256), 0, stream>>>(L, R, out);
}